// Round 2
// baseline (251.414 us; speedup 1.0000x reference)
//
#include <hip/hip_runtime.h>

#define N_TOK   524288
#define KC      256
#define D       32
#define EPSF    1e-6f
#define TPT     128                // tokens per tile (was 64)
#define NTILES  (N_TOK / TPT)      // 4096
#define NBLK    512                // 2 blocks/CU x 256 CUs, all resident
#define BLKT    256

// ---------------- main kernel: argmin + rotation + per-block histogram ----------------
__global__ __launch_bounds__(BLKT, 2) void vq_main(
    const float* __restrict__ x, const float* __restrict__ cb,
    float* __restrict__ out_rot, float* __restrict__ out_idx,
    float* __restrict__ ws_hist, float* __restrict__ out_cnt, int use_ws)
{
    __shared__ float ct[D][KC];       // codebook transposed (32 KB)
    __shared__ float c2s[KC];         // ||c||^2, numpy pairwise order (1 KB)
    __shared__ float xt[2][D][TPT];   // x tile transposed, double-buffered (32 KB)
    __shared__ float x2s[2][TPT];     // ||x||^2 per token (1 KB)
    __shared__ float hist[KC];        // per-block histogram (1 KB)
    // total ~67.5 KB -> 2 blocks/CU

    const int tid  = threadIdx.x;

    // ---- stage codebook transposed + c2 (numpy pairwise), zero hist ----
    {
#pragma clang fp contract(off)
        const float4* cb4 = (const float4*)(cb + (size_t)tid * D);
        float4 r[8];
#pragma unroll
        for (int j = 0; j < 8; j++) r[j] = cb4[j];
        float t[32];
#pragma unroll
        for (int j = 0; j < 8; j++) {
            t[4 * j + 0] = r[j].x * r[j].x;
            t[4 * j + 1] = r[j].y * r[j].y;
            t[4 * j + 2] = r[j].z * r[j].z;
            t[4 * j + 3] = r[j].w * r[j].w;
        }
        float pr[8];
#pragma unroll
        for (int j = 0; j < 8; j++)
            pr[j] = ((t[j] + t[j + 8]) + t[j + 16]) + t[j + 24];
        c2s[tid] = ((pr[0] + pr[1]) + (pr[2] + pr[3])) + ((pr[4] + pr[5]) + (pr[6] + pr[7]));
#pragma unroll
        for (int j = 0; j < 8; j++) {
            ct[4 * j + 0][tid] = r[j].x;
            ct[4 * j + 1][tid] = r[j].y;
            ct[4 * j + 2][tid] = r[j].z;
            ct[4 * j + 3][tid] = r[j].w;
        }
        hist[tid] = 0.f;
    }

    const int tt  = tid >> 4;          // token group 0..15 (8 tokens each)
    const int tc  = tid & 15;          // code  group 0..15 (4x4 codes, stride 64)
    const int tok = tid >> 1;          // staging/epilogue token (block-local, 0..127)
    const int sub = tid & 1;           // dim half 0..1 (16 dims each)
    const int k0  = sub * 16;

    // stage one tile (held in regs) into xt[buf]; x2 computed IN REGISTERS with the
    // exact numpy pairwise order: pr[j] = ((t[j]+t[j+8])+t[j+16])+t[j+24].
    // sub0 holds t[0..15], sub1 holds t[16..31]; partner values via shfl_xor(1).
    auto stage = [&](int buf, float4 r0, float4 r1, float4 r2, float4 r3) {
#pragma clang fp contract(off)
        float xs[16] = {r0.x, r0.y, r0.z, r0.w, r1.x, r1.y, r1.z, r1.w,
                        r2.x, r2.y, r2.z, r2.w, r3.x, r3.y, r3.z, r3.w};
#pragma unroll
        for (int j = 0; j < 16; j++) xt[buf][k0 + j][tok] = xs[j];
        float sq[16];
#pragma unroll
        for (int j = 0; j < 16; j++) sq[j] = xs[j] * xs[j];
        float pr[8];
#pragma unroll
        for (int j = 0; j < 8; j++) {
            float a = sq[j] + sq[j + 8];               // sub0: t[j] + t[j+8]
            float u = __shfl_xor(sq[j], 1, 64);        // sub0 gets t[16+j]
            float v = __shfl_xor(sq[j + 8], 1, 64);    // sub0 gets t[24+j]
            pr[j] = (a + u) + v;                       // ((t[j]+t[j+8])+t[j+16])+t[j+24]
        }
        float x2v = ((pr[0] + pr[1]) + (pr[2] + pr[3])) + ((pr[4] + pr[5]) + (pr[6] + pr[7]));
        if (sub == 0) x2s[buf][tok] = x2v;
    };

    // ---- prologue: load + stage tile0 ----
    float4 aC0, aC1, aC2, aC3;
    {
        const float4* xg = (const float4*)(x + (size_t)blockIdx.x * TPT * D + (size_t)tid * 16);
        aC0 = xg[0]; aC1 = xg[1]; aC2 = xg[2]; aC3 = xg[3];
    }
    stage(0, aC0, aC1, aC2, aC3);
    __syncthreads();

    int cur = 0;
    for (int tile = blockIdx.x; tile < NTILES; tile += gridDim.x) {
        const int nt = tile + gridDim.x;
        const bool hasN = (nt < NTILES);               // block-uniform
        float4 aN0 = aC0, aN1 = aC1, aN2 = aC2, aN3 = aC3;
        if (hasN) {                                    // issue next-tile loads early
            const float4* xg = (const float4*)(x + (size_t)nt * TPT * D + (size_t)tid * 16);
            aN0 = xg[0]; aN1 = xg[1]; aN2 = xg[2]; aN3 = xg[3];
        }

        // ---- scores: 8 tokens x 16 codes per thread, single fused k-loop ----
        float x4[8];
#pragma unroll
        for (int i = 0; i < 8; i++) x4[i] = x2s[cur][tt * 8 + i];

        float acc[8][16];
#pragma unroll
        for (int i = 0; i < 8; i++)
#pragma unroll
            for (int j = 0; j < 16; j++) acc[i][j] = 0.f;

        // sequential fused-FMA over k ascending == same chain per (token,code) as before.
#pragma unroll 4
        for (int k = 0; k < D; k++) {
            const float4 xv0 = *(const float4*)&xt[cur][k][tt * 8];
            const float4 xv1 = *(const float4*)&xt[cur][k][tt * 8 + 4];
            const float4 v0 = *(const float4*)&ct[k][tc * 4];
            const float4 v1 = *(const float4*)&ct[k][64 + tc * 4];
            const float4 v2 = *(const float4*)&ct[k][128 + tc * 4];
            const float4 v3 = *(const float4*)&ct[k][192 + tc * 4];
            const float xs[8]  = {xv0.x, xv0.y, xv0.z, xv0.w, xv1.x, xv1.y, xv1.z, xv1.w};
            const float cs[16] = {v0.x, v0.y, v0.z, v0.w, v1.x, v1.y, v1.z, v1.w,
                                  v2.x, v2.y, v2.z, v2.w, v3.x, v3.y, v3.z, v3.w};
#pragma unroll
            for (int i = 0; i < 8; i++)
#pragma unroll
                for (int j = 0; j < 16; j++)
                    acc[i][j] = __builtin_fmaf(xs[i], cs[j], acc[i][j]);
        }

        // d2 = fl(fl(x2 - 2*xc) + c2) — same op order (2*acc is exact, so contraction
        // cannot change rounding); per-thread codes ascending, strict < keeps lowest index.
        float bestv[8];
        int   besti[8];
#pragma unroll
        for (int i = 0; i < 8; i++) { bestv[i] = 3.4e38f; besti[i] = 0x7fffffff; }
#pragma unroll
        for (int j = 0; j < 16; j++) {
            const int code = (j >> 2) * 64 + tc * 4 + (j & 3);
            const float c2v = c2s[code];
#pragma unroll
            for (int i = 0; i < 8; i++) {
                float t2 = x4[i] - 2.0f * acc[i][j];
                float s  = t2 + c2v;
                if (s < bestv[i]) { bestv[i] = s; besti[i] = code; }
            }
        }

        // cross-lane argmin over the 16 code-threads; index tie-break = global first-min
#pragma unroll
        for (int m = 1; m < 16; m <<= 1) {
#pragma unroll
            for (int i = 0; i < 8; i++) {
                float ov = __shfl_xor(bestv[i], m, 64);
                int   oi = __shfl_xor(besti[i], m, 64);
                if (ov < bestv[i] || (ov == bestv[i] && oi < besti[i])) {
                    bestv[i] = ov; besti[i] = oi;
                }
            }
        }

        // winner for epilogue token tok=tid>>1: its group is tt=tid>>4 (same group),
        // slot i=(tid>>1)&7. Static 8->1 select tree (no runtime array index).
        const bool b0 = (tid >> 1) & 1;
        const bool b1 = (tid >> 2) & 1;
        const bool b2 = (tid >> 3) & 1;
        const int s0  = b0 ? besti[1] : besti[0];
        const int s1  = b0 ? besti[3] : besti[2];
        const int s2  = b0 ? besti[5] : besti[4];
        const int s3  = b0 ? besti[7] : besti[6];
        const int s01 = b1 ? s1 : s0;
        const int s23 = b1 ? s3 : s2;
        const int bi  = b2 ? s23 : s01;

        // ---- rotation epilogue: 2 lanes per token, 16 dims each; x already in regs ----
        {
            const size_t gtok = (size_t)tile * TPT + tok;
            const float4* cg = (const float4*)(cb + (size_t)bi * D + k0);
            float4 c0 = cg[0], c1 = cg[1], c2f = cg[2], c3 = cg[3];

            float xs16[16] = {aC0.x, aC0.y, aC0.z, aC0.w, aC1.x, aC1.y, aC1.z, aC1.w,
                              aC2.x, aC2.y, aC2.z, aC2.w, aC3.x, aC3.y, aC3.z, aC3.w};
            float cs16[16] = {c0.x, c0.y, c0.z, c0.w, c1.x, c1.y, c1.z, c1.w,
                              c2f.x, c2f.y, c2f.z, c2f.w, c3.x, c3.y, c3.z, c3.w};

            float px2 = 0.f, pc2 = 0.f;
#pragma unroll
            for (int j = 0; j < 16; j++) {
                px2 = fmaf(xs16[j], xs16[j], px2);
                pc2 = fmaf(cs16[j], cs16[j], pc2);
            }
            float x2 = px2 + __shfl_xor(px2, 1, 64);
            float c2 = pc2 + __shfl_xor(pc2, 1, 64);
            const float inx = 1.f / fmaxf(sqrtf(x2), EPSF);
            const float inc = 1.f / fmaxf(sqrtf(c2), EPSF);

            float us16[16], qs16[16], ws16[16];
            float pw2 = 0.f;
#pragma unroll
            for (int j = 0; j < 16; j++) {
                us16[j] = xs16[j] * inx;
                qs16[j] = cs16[j] * inc;
                ws16[j] = us16[j] + qs16[j];
                pw2 = fmaf(ws16[j], ws16[j], pw2);
            }
            float w2 = pw2 + __shfl_xor(pw2, 1, 64);
            const float inw = 1.f / fmaxf(sqrtf(w2), EPSF);

            float pew = 0.f, peu = 0.f;
#pragma unroll
            for (int j = 0; j < 16; j++) {
                ws16[j] *= inw;
                pew = fmaf(xs16[j], ws16[j], pew);
                peu = fmaf(xs16[j], us16[j], peu);
            }
            float ew = pew + __shfl_xor(pew, 1, 64);
            float eu = peu + __shfl_xor(peu, 1, 64);

            float ro[16];
#pragma unroll
            for (int j = 0; j < 16; j++)
                ro[j] = xs16[j] - 2.f * ew * ws16[j] + 2.f * eu * qs16[j];

            float4* og = (float4*)(out_rot + gtok * D + k0);
            og[0] = make_float4(ro[0],  ro[1],  ro[2],  ro[3]);
            og[1] = make_float4(ro[4],  ro[5],  ro[6],  ro[7]);
            og[2] = make_float4(ro[8],  ro[9],  ro[10], ro[11]);
            og[3] = make_float4(ro[12], ro[13], ro[14], ro[15]);

            if (sub == 0) {
                out_idx[gtok] = (float)bi;
                atomicAdd(&hist[bi], 1.f);
            }
        }

        // stage next tile into the other buffer; ONE barrier per tile.
        if (hasN) stage(cur ^ 1, aN0, aN1, aN2, aN3);
        __syncthreads();
        aC0 = aN0; aC1 = aN1; aC2 = aN2; aC3 = aN3;
        cur ^= 1;
    }

    // ---- flush per-block histogram ----
    if (use_ws) ws_hist[(size_t)blockIdx.x * KC + tid] = hist[tid];
    else        atomicAdd(&out_cnt[tid], hist[tid]);
}

// ---------------- tiny reduce: 512 block-partials -> 256 counts ----------------
__global__ __launch_bounds__(256) void vq_reduce(const float* __restrict__ ws,
                                                 float* __restrict__ out_cnt)
{
    const int c = blockIdx.x * 8 + (threadIdx.x >> 5);  // code
    const int l = threadIdx.x & 31;                     // lane within code-group
    float s = 0.f;
    for (int b = l; b < NBLK; b += 32) s += ws[(size_t)b * KC + c];
#pragma unroll
    for (int m = 1; m < 32; m <<= 1) s += __shfl_xor(s, m, 64);
    if (l == 0) out_cnt[c] = s;
}

extern "C" void kernel_launch(void* const* d_in, const int* in_sizes, int n_in,
                              void* d_out, int out_size, void* d_ws, size_t ws_size,
                              hipStream_t stream)
{
    const float* x  = (const float*)d_in[0];
    const float* cb = (const float*)d_in[1];
    float* out      = (float*)d_out;
    float* out_rot  = out;                                   // [524288*32]
    float* out_idx  = out + (size_t)N_TOK * D;               // [524288] (indices as float)
    float* out_cnt  = out_idx + N_TOK;                       // [256]

    const size_t ws_need = (size_t)NBLK * KC * sizeof(float);
    const int use_ws = (ws_size >= ws_need) ? 1 : 0;
    if (!use_ws) hipMemsetAsync(out_cnt, 0, KC * sizeof(float), stream);

    vq_main<<<NBLK, BLKT, 0, stream>>>(x, cb, out_rot, out_idx,
                                       (float*)d_ws, out_cnt, use_ws);
    if (use_ws) vq_reduce<<<32, 256, 0, stream>>>((const float*)d_ws, out_cnt);
}